// Round 7
// baseline (200.079 us; speedup 1.0000x reference)
//
#include <hip/hip_runtime.h>
#include <hip/hip_bf16.h>

// MultiHeadSelfAttention: B=2, S=2048, D=1024, H=16, DK=64
// R7: (1) P packed via u+0x8000 + v_perm_b32 (3 insts / 2 elems, was ~10);
//     (2) attn 256-thread blocks: wave-pairs split k-range [0,16)/[16,32),
//         additive O/l merge via LDS at end (static-max softmax => no rescale);
//         2 waves/SIMD so VALU(exp2) overlaps MFMA across waves;
//     (3) QKV weights pre-permuted to [which][h][dk] (QSCALE folded) => epilogue
//         col decode is shifts/ands, single selected store base.

using bf16 = __hip_bfloat16;
typedef __attribute__((ext_vector_type(8))) short bf16x8;   // 8 bf16 = 4 VGPRs
typedef __attribute__((ext_vector_type(4))) float f32x4;

#define QSCALE 0.18033688011112042f   // (1/sqrt(64)) * log2(e)

static __device__ __forceinline__ f32x4 mfma_bf16(bf16x8 a, bf16x8 b, f32x4 c) {
    return __builtin_amdgcn_mfma_f32_16x16x32_bf16(a, b, c, 0, 0, 0);
}

static __device__ __forceinline__ void gld_lds16(const void* g, void* s) {
    __builtin_amdgcn_global_load_lds(
        (const __attribute__((address_space(1))) unsigned int*)g,
        (__attribute__((address_space(3))) unsigned int*)s,
        16, 0, 0);
}

// pack two fp32 -> bf16x2 (round-half-up), 3 VALU ops
static __device__ __forceinline__ unsigned int pk_bf16(float lo, float hi) {
    unsigned int ul = __builtin_bit_cast(unsigned int, lo) + 0x8000u;
    unsigned int uh = __builtin_bit_cast(unsigned int, hi) + 0x8000u;
    return __builtin_amdgcn_perm(uh, ul, 0x07060302u);   // {ul.hi16, uh.hi16}
}

// ---------------- fused prep ----------------
// blocks [0,4096): cast x; [4096,7168): transpose+permute wqkv; [7168,8192): transpose wo
__global__ void prep_kernel(const float* __restrict__ x, bf16* __restrict__ xb,
                            const float* __restrict__ wqkv, bf16* __restrict__ wqkvT,
                            const float* __restrict__ wo, bf16* __restrict__ woT) {
    __shared__ float tile[32][33];
    int blk = blockIdx.x;
    if (blk < 4096) {
        int i = blk * 256 + threadIdx.x;
        float4 f = reinterpret_cast<const float4*>(x)[i];
        xb[4*i+0] = __float2bfloat16(f.x);
        xb[4*i+1] = __float2bfloat16(f.y);
        xb[4*i+2] = __float2bfloat16(f.z);
        xb[4*i+3] = __float2bfloat16(f.w);
        return;
    }
    int xo = threadIdx.x & 31, yo = threadIdx.x >> 5;   // (32,8)
    if (blk < 7168) {
        // wqkv [1024][3072] -> wqkvT row' = which*1024 + h*64 + dk (QSCALE folded for Q)
        int idx = blk - 4096;
        int c0 = (idx % 96) * 32, r0 = (idx / 96) * 32;
#pragma unroll
        for (int i = 0; i < 32; i += 8)
            tile[yo + i][xo] = wqkv[(size_t)(r0 + yo + i) * 3072 + c0 + xo];
        __syncthreads();
#pragma unroll
        for (int i = 0; i < 32; i += 8) {
            int c = c0 + yo + i;
            int hh = c / 192, rem = c - hh * 192;
            int which = rem >> 6, dk = rem & 63;
            int rowp = which * 1024 + hh * 64 + dk;
            float sc = (which == 0) ? QSCALE : 1.0f;
            wqkvT[(size_t)rowp * 1024 + r0 + xo] = __float2bfloat16(tile[xo][yo + i] * sc);
        }
    } else {
        int idx = blk - 7168;
        int c0 = (idx & 31) * 32, r0 = (idx >> 5) * 32;
#pragma unroll
        for (int i = 0; i < 32; i += 8)
            tile[yo + i][xo] = wo[(size_t)(r0 + yo + i) * 1024 + c0 + xo];
        __syncthreads();
#pragma unroll
        for (int i = 0; i < 32; i += 8)
            woT[(size_t)(c0 + yo + i) * 1024 + r0 + xo] = __float2bfloat16(tile[xo][yo + i]);
    }
}

// ---------------- transpose V + dual-slice kpos permutation ----------------
__global__ void transpose_v_kernel(const bf16* __restrict__ in, bf16* __restrict__ out) {
    __shared__ bf16 t[64][72];
    const int bh = blockIdx.y, s0 = blockIdx.x * 64;
    const int r = threadIdx.x >> 2, c16 = (threadIdx.x & 3) * 16;
    const uint4* src = (const uint4*)(in + ((size_t)bh * 2048 + s0 + r) * 64 + c16);
    uint4 a0 = src[0], a1 = src[1];
    *(uint4*)&t[r][c16] = a0;
    *(uint4*)&t[r][c16 + 8] = a1;
    __syncthreads();
    bf16 tmp[16];
#pragma unroll
    for (int ii = 0; ii < 16; ++ii) {
        int i = c16 + ii;
        int a = i >> 5, rem = i & 31, q = rem >> 3, jj = rem & 7;
        int sp = a * 32 + q * 4 + (jj < 4 ? jj : 16 + jj - 4);
        tmp[ii] = t[sp][r];
    }
    uint4* dst = (uint4*)(out + ((size_t)bh * 64 + r) * 2048 + s0 + c16);
    dst[0] = ((uint4*)tmp)[0];
    dst[1] = ((uint4*)tmp)[1];
}

// ---------------- GEMM: C[M,N] = A[M,K] @ Bt[N,K]^T ----------------
template <int EPI, int TM, int MINW>
__global__ __launch_bounds__(256, MINW)
void gemm_bt_kernel(const bf16* __restrict__ A, const bf16* __restrict__ Bt,
                    int M, int N, int K,
                    const float* __restrict__ bias, const float* __restrict__ gamma,
                    bf16* __restrict__ Qout, bf16* __restrict__ Kout, bf16* __restrict__ Vout,
                    float* __restrict__ Cout) {
    constexpr int MI = TM / 32;
    constexpr int CA = TM / 32;
    __shared__ __align__(16) bf16 As[TM * 64];
    __shared__ __align__(16) bf16 Bs[128 * 64];

    const int tid  = threadIdx.x;
    const int wave = tid >> 6, lane = tid & 63;
    const int quad = lane >> 4, l16 = lane & 15;
    const int wr = wave >> 1, wc = wave & 1;
    const int bm = blockIdx.y, bn = blockIdx.x;

    f32x4 acc[MI][4] = {};

    const int crow = lane >> 3;
    const int sblk = (lane & 7) ^ (crow & 7);
    const bf16* gA[CA]; const bf16* gB[4]; bf16* lA[CA]; bf16* lB[4];
#pragma unroll
    for (int c = 0; c < CA; ++c) {
        int ch = wave * CA + c;
        gA[c] = A + (size_t)(bm * TM + ch * 8 + crow) * K + sblk * 8;
        lA[c] = As + ch * 512 + lane * 8;
    }
#pragma unroll
    for (int c = 0; c < 4; ++c) {
        int ch = wave * 4 + c;
        gB[c] = Bt + (size_t)(bn * 128 + ch * 8 + crow) * K + sblk * 8;
        lB[c] = Bs + ch * 512 + lane * 8;
    }
    const int xr = l16 & 7;

    for (int k0 = 0; k0 < K; k0 += 64) {
#pragma unroll
        for (int c = 0; c < CA; ++c) gld_lds16(gA[c] + k0, lA[c]);
#pragma unroll
        for (int c = 0; c < 4; ++c) gld_lds16(gB[c] + k0, lB[c]);
        __syncthreads();
#pragma unroll
        for (int ks = 0; ks < 2; ++ks) {
            bf16x8 af[MI], bfr[4];
#pragma unroll
            for (int mi = 0; mi < MI; ++mi)
                af[mi] = *(const bf16x8*)(As + (wr * (TM/2) + mi * 16 + l16) * 64 + ((4 * ks + quad) ^ xr) * 8);
#pragma unroll
            for (int ni = 0; ni < 4; ++ni)
                bfr[ni] = *(const bf16x8*)(Bs + (wc * 64 + ni * 16 + l16) * 64 + ((4 * ks + quad) ^ xr) * 8);
#pragma unroll
            for (int mi = 0; mi < MI; ++mi)
#pragma unroll
                for (int ni = 0; ni < 4; ++ni)
                    acc[mi][ni] = mfma_bf16(af[mi], bfr[ni], acc[mi][ni]);
        }
        __syncthreads();
    }

#pragma unroll
    for (int mi = 0; mi < MI; ++mi) {
#pragma unroll
        for (int ni = 0; ni < 4; ++ni) {
            int col = bn * 128 + wc * 64 + ni * 16 + l16;
            if (EPI == 0) {
                int which = col >> 10, hh = (col >> 6) & 15, dk = col & 63;
                float bsc = (which == 0) ? QSCALE : 1.0f;
                float bv = bias[hh * 192 + which * 64 + dk] * bsc;
                bf16* dst = (which == 0) ? Qout : ((which == 1) ? Kout : Vout);
#pragma unroll
                for (int r = 0; r < 4; ++r) {
                    int row = bm * TM + wr * (TM/2) + mi * 16 + quad * 4 + r;
                    int b = row >> 11, s = row & 2047;   // S = 2048
                    dst[(((size_t)b * 16 + hh) * 2048 + s) * 64 + dk] =
                        __float2bfloat16(acc[mi][ni][r] + bv);
                }
            } else {
                float g1 = gamma[col] + 1.0f, bv = bias[col];
#pragma unroll
                for (int r = 0; r < 4; ++r) {
                    int row = bm * TM + wr * (TM/2) + mi * 16 + quad * 4 + r;
                    Cout[(size_t)row * N + col] = g1 * (acc[mi][ni][r] + bv);
                }
            }
        }
    }
}

// ---------------- flash attention: 4 waves = 2 q-halves x 2 k-halves ----------------
// grid (S/128, B*H), block 256. Wave (qw,kh): q rows [q0+64qw, +64), k tiles
// [16kh, 16kh+16). Static-max softmax => partials additive; merge via LDS at end.
__global__ __launch_bounds__(256, 2)
void attn_kernel(const bf16* __restrict__ Qb, const bf16* __restrict__ Kb,
                 const bf16* __restrict__ Vtp, const int* __restrict__ mask,
                 bf16* __restrict__ Aout) {
    __shared__ __align__(16) unsigned char smem[66560];
    bf16* KsB = (bf16*)smem;                   // [kh*2+buf][4096]
    bf16* VsB = (bf16*)(smem + 32768);         // [kh*2+buf][4096]
    float* BiasB = (float*)(smem + 65536);     // [kh*2+buf][64]

    const int bh = blockIdx.y;
    const int b = bh >> 4, h = bh & 15;
    const int q0 = blockIdx.x * 128;
    const int tid = threadIdx.x;
    const int wave = tid >> 6, lane = tid & 63;
    const int quad = lane >> 4, l16 = lane & 15;
    const int xr = l16 & 7;
    const int qw = wave & 1, kh = wave >> 1;

    // Q fragments
    bf16x8 aq[4][2];
#pragma unroll
    for (int m = 0; m < 4; ++m) {
        const bf16* qp = Qb + ((size_t)bh * 2048 + q0 + qw * 64 + m * 16 + l16) * 64;
        aq[m][0] = *(const bf16x8*)(qp + quad * 8);
        aq[m][1] = *(const bf16x8*)(qp + 32 + quad * 8);
    }

    bf16x8 ones;
#pragma unroll
    for (int j = 0; j < 8; ++j) ones[j] = (short)0x3F80;

    f32x4 O[4][4] = {};
    f32x4 Lacc[4] = {};

    // DMA staging (per k-half pair; qw plays R6's "wave" role)
    const int r8 = lane >> 3, b8 = lane & 7;
    const int srcb = b8 ^ r8;
    const bf16* gK = Kb  + ((size_t)bh * 2048 + kh * 1024 + qw * 8 + r8) * 64 + srcb * 8;
    const bf16* gV = Vtp + ((size_t)bh * 64 + qw * 8 + r8) * 2048 + kh * 1024 + srcb * 8;
    bf16* lK[2][4]; bf16* lV[2][4];
#pragma unroll
    for (int p = 0; p < 2; ++p)
#pragma unroll
        for (int c = 0; c < 4; ++c) {
            lK[p][c] = KsB + (kh * 2 + p) * 4096 + c * 1024 + qw * 512 + lane * 8;
            lV[p][c] = VsB + (kh * 2 + p) * 4096 + c * 1024 + qw * 512 + lane * 8;
        }

    // prologue: tile 0 of this k-half -> buf0; bias; prefetch next mask
    int mreg = 0;
#pragma unroll
    for (int c = 0; c < 4; ++c) {
        gld_lds16(gK + c * 1024, lK[0][c]);
        gld_lds16(gV + (size_t)c * 32768, lV[0][c]);
    }
    if (qw == 0) {
        BiasB[(kh * 2) * 64 + lane] = mask[b * 2048 + kh * 1024 + lane] ? -24.0f : -1e30f;
        mreg = mask[b * 2048 + kh * 1024 + 64 + lane];
    }

    for (int kt = 0; kt < 16; ++kt) {
        __syncthreads();
        const int cur = kt & 1, nxt = cur ^ 1;

        if (kt + 1 < 16) {
#pragma unroll
            for (int c = 0; c < 4; ++c) {
                gld_lds16(gK + (size_t)(kt + 1) * 4096 + c * 1024, lK[nxt][c]);
                gld_lds16(gV + (kt + 1) * 64 + (size_t)c * 32768, lV[nxt][c]);
            }
            if (qw == 0) BiasB[(kh * 2 + nxt) * 64 + lane] = mreg ? -24.0f : -1e30f;
        }
        if (kt + 2 < 16 && qw == 0) mreg = mask[b * 2048 + kh * 1024 + (kt + 2) * 64 + lane];

        const bf16* Ksc = KsB + (kh * 2 + cur) * 4096;
        const bf16* Vsc = VsB + (kh * 2 + cur) * 4096;
        const float* Bic = BiasB + (kh * 2 + cur) * 64;

        f32x4 bias4[4];
        bf16x8 bk[4][2];
#pragma unroll
        for (int kt4 = 0; kt4 < 4; ++kt4) {
            bias4[kt4] = *(const f32x4*)(Bic + kt4 * 16 + quad * 4);
            const bf16* kp = Ksc + (kt4 * 16 + l16) * 64;
            bk[kt4][0] = *(const bf16x8*)(kp + (quad ^ xr) * 8);
            bk[kt4][1] = *(const bf16x8*)(kp + ((quad + 4) ^ xr) * 8);
        }
        bf16x8 bv8[2][4];
#pragma unroll
        for (int a = 0; a < 2; ++a)
#pragma unroll
            for (int nt = 0; nt < 4; ++nt)
                bv8[a][nt] = *(const bf16x8*)(Vsc + (nt * 16 + l16) * 64 + ((a * 4 + quad) ^ xr) * 8);

#pragma unroll
        for (int m = 0; m < 4; ++m) {
            f32x4 sv[4];
#pragma unroll
            for (int kt4 = 0; kt4 < 4; ++kt4) {
                f32x4 c = {0.f, 0.f, 0.f, 0.f};
                c = mfma_bf16(bk[kt4][0], aq[m][0], c);
                c = mfma_bf16(bk[kt4][1], aq[m][1], c);
                sv[kt4] = c;
            }
            float p[4][4];
#pragma unroll
            for (int kt4 = 0; kt4 < 4; ++kt4)
#pragma unroll
                for (int r = 0; r < 4; ++r)
                    p[kt4][r] = __builtin_amdgcn_exp2f(sv[kt4][r] + bias4[kt4][r]);

#pragma unroll
            for (int a = 0; a < 2; ++a) {
                uint4 uv;
                uv.x = pk_bf16(p[2*a][0],   p[2*a][1]);
                uv.y = pk_bf16(p[2*a][2],   p[2*a][3]);
                uv.z = pk_bf16(p[2*a+1][0], p[2*a+1][1]);
                uv.w = pk_bf16(p[2*a+1][2], p[2*a+1][3]);
                bf16x8 pa = __builtin_bit_cast(bf16x8, uv);
                Lacc[m] = mfma_bf16(pa, ones, Lacc[m]);
#pragma unroll
                for (int nt = 0; nt < 4; ++nt)
                    O[m][nt] = mfma_bf16(pa, bv8[a][nt], O[m][nt]);
            }
        }
    }

    // merge k-halves: kh=1 writes partials, kh=0 adds (stride 81 dw: conflict-free)
    __syncthreads();
    float* mg = (float*)smem;
    float* mp = mg + (qw * 64 + lane) * 81;
    if (kh == 1) {
#pragma unroll
        for (int m = 0; m < 4; ++m) {
#pragma unroll
            for (int nt = 0; nt < 4; ++nt)
#pragma unroll
                for (int r = 0; r < 4; ++r) mp[m * 16 + nt * 4 + r] = O[m][nt][r];
#pragma unroll
            for (int r = 0; r < 4; ++r) mp[64 + m * 4 + r] = Lacc[m][r];
        }
    }
    __syncthreads();
    if (kh == 0) {
#pragma unroll
        for (int m = 0; m < 4; ++m) {
#pragma unroll
            for (int nt = 0; nt < 4; ++nt)
#pragma unroll
                for (int r = 0; r < 4; ++r) O[m][nt][r] += mp[m * 16 + nt * 4 + r];
#pragma unroll
            for (int r = 0; r < 4; ++r) Lacc[m][r] += mp[64 + m * 4 + r];
        }
#pragma unroll
        for (int m = 0; m < 4; ++m) {
            float inv[4];
#pragma unroll
            for (int r = 0; r < 4; ++r) inv[r] = __builtin_amdgcn_rcpf(Lacc[m][r]);
#pragma unroll
            for (int nt = 0; nt < 4; ++nt) {
#pragma unroll
                for (int r = 0; r < 4; ++r) {
                    int row = q0 + qw * 64 + m * 16 + quad * 4 + r;
                    Aout[((size_t)b * 2048 + row) * 1024 + h * 64 + nt * 16 + l16] =
                        __float2bfloat16(O[m][nt][r] * inv[r]);
                }
            }
        }
    }
}

// ---------------- launcher ----------------
extern "C" void kernel_launch(void* const* d_in, const int* in_sizes, int n_in,
                              void* d_out, int out_size, void* d_ws, size_t ws_size,
                              hipStream_t stream) {
    const float* x     = (const float*)d_in[0];
    const float* gamma = (const float*)d_in[1];
    const int*   mask  = (const int*)d_in[2];
    const float* wqkv  = (const float*)d_in[3];
    const float* bqkv  = (const float*)d_in[4];
    const float* wo    = (const float*)d_in[5];
    const float* bo    = (const float*)d_in[6];
    float* out = (float*)d_out;

    char* ws = (char*)d_ws;
    const size_t MB = 1u << 20;
    bf16* xb    = (bf16*)(ws);            //  8 MB
    bf16* wqkvT = (bf16*)(ws + 8 * MB);   //  6 MB (permuted rows, QSCALE folded)
    bf16* woT   = (bf16*)(ws + 14 * MB);  //  2 MB
    bf16* Qb    = (bf16*)(ws + 16 * MB);  //  8 MB
    bf16* Kb    = (bf16*)(ws + 24 * MB);  //  8 MB
    bf16* Vt    = (bf16*)(ws + 32 * MB);  //  8 MB (transposed+permuted)
    bf16* Vtmp  = (bf16*)(ws + 40 * MB);  //  8 MB (dead after transpose)
    bf16* attn  = (bf16*)(ws + 40 * MB);  //  8 MB (reuses Vtmp slot)

    prep_kernel<<<8192, 256, 0, stream>>>(x, xb, wqkv, wqkvT, wo, woT);

    gemm_bt_kernel<0, 128, 3><<<dim3(24, 32), 256, 0, stream>>>(
        xb, wqkvT, 4096, 3072, 1024, bqkv, nullptr, Qb, Kb, Vtmp, nullptr);

    transpose_v_kernel<<<dim3(32, 32), 256, 0, stream>>>(Vtmp, Vt);

    attn_kernel<<<dim3(16, 32), 256, 0, stream>>>(Qb, Kb, Vt, mask, attn);

    gemm_bt_kernel<1, 64, 4><<<dim3(8, 64), 256, 0, stream>>>(
        attn, woT, 4096, 1024, 1024, bo, gamma, nullptr, nullptr, nullptr, out);
}